// Round 10
// baseline (156.710 us; speedup 1.0000x reference)
//
#include <hip/hip_runtime.h>

#define IMG    512
#define KSZ    11
#define HALO   5
#define BW     256                  // strip width = blockDim.x
#define BH     64                   // output rows per block
#define INW    (BW + 2*HALO)        // 266 staged columns
#define ROWS   (BH + 2*HALO)        // 74 input rows walked
#define CHUNK  11                   // rows staged per buffer == ring depth
#define NCHUNK ((ROWS + CHUNK - 1) / CHUNK)   // 7

// Packed fp32 (proven encoding: all operands are 64-bit VGPR pairs).
// NOTE (R9 lesson): op_sel broadcast from a single scalar VGPR does NOT
// assemble — src0 must be a pair. Keep (g,g) pairs.
__device__ __forceinline__ float2 pk_fma(float2 a, float2 b, float2 c) {
    float2 d;
    asm("v_pk_fma_f32 %0, %1, %2, %3" : "=v"(d) : "v"(a), "v"(b), "v"(c));
    return d;
}
__device__ __forceinline__ float2 pk_mul(float2 a, float2 b) {
    float2 d;
    asm("v_pk_mul_f32 %0, %1, %2" : "=v"(d) : "v"(a), "v"(b));
    return d;
}

// No min-waves arg (round-3 lesson: forcing VGPR down spills the ring).
__global__ __launch_bounds__(256)
void dssim_strip_kernel(const float* __restrict__ x,
                        const float* __restrict__ y,
                        const float* __restrict__ kern,
                        float* __restrict__ out)
{
    __shared__ float  sg[KSZ];
    // Staged fields: squares/cross computed ONCE per input pixel at commit
    // (was recomputed 11x per pixel in the H-pass = 6 ALU-cyc/tap wasted).
    __shared__ float2 sxy[CHUNK][INW + 1];   // (x, y)      23.5 KB
    __shared__ float2 ssq[CHUNK][INW + 1];   // (x^2, y^2)  23.5 KB
    __shared__ float  sxc[CHUNK][INW + 3];   // x*y         11.8 KB

    const int tid = threadIdx.x;

    // Recover separable 1D gaussian: row sums of the 2D kernel
    // (k2d[i][j] = g[i]*g[j], sum_j = g[i] since sum(g)==1).
    if (tid < KSZ) {
        float s = 0.f;
        #pragma unroll
        for (int j = 0; j < KSZ; ++j) s += kern[tid * KSZ + j];
        sg[tid] = s;
    }
    __syncthreads();

    // Symmetric taps g[k]==g[10-k]: 6 (g,g) pairs for pk ops.
    float2 gg[HALO + 1];
    #pragma unroll
    for (int k = 0; k <= HALO; ++k) gg[k] = make_float2(sg[k], sg[k]);

    const int plane = blockIdx.z;                   // n*C + c
    const int base  = plane * IMG * IMG;            // < 25.2M: fits int32
    const int col0  = blockIdx.x * BW;
    const int row0  = blockIdx.y * BH;

    // This thread's staged column (computed once).
    const int  gc  = col0 - HALO + tid;
    const bool cok = (gc >= 0) && (gc < IMG);
    // Remainder columns (INW-BW=10 per row) flattened over threads 0..109:
    const bool eact = (tid < (INW - BW) * CHUNK);
    const int  je   = tid / (INW - BW);             // chunk-local row 0..10
    const int  ce   = BW + tid % (INW - BW);        // LDS col 256..265
    const int  gce  = col0 - HALO + ce;
    const bool ceok = eact && (gce >= 0) && (gce < IMG);

    // Register ring: 11 rows of {(ax,ay),(axx,ayy),axy} — static indexing.
    float2 ringA[CHUNK];
    float2 ringS[CHUNK];
    float  ringC[CHUNK];
    // Prefetch registers for the next chunk (issue-early / write-late).
    float2 pf[CHUNK];
    float2 pfe;

    const float C1 = 1e-4f;    // 0.01^2
    const float C2 = 9e-4f;    // 0.03^2
    float local = 0.f;

    auto prefetch = [&](int cc) {
        #pragma unroll
        for (int j = 0; j < CHUNK; ++j) {
            const int i  = cc * CHUNK + j;
            const int gr = row0 - HALO + i;
            float xv = 0.f, yv = 0.f;
            if (i < ROWS && gr >= 0 && gr < IMG && cok) {
                const int off = base + gr * IMG + gc;
                xv = x[off];
                yv = y[off];
            }
            pf[j] = make_float2(xv, yv);
        }
        const int ie  = cc * CHUNK + je;
        const int gre = row0 - HALO + ie;
        float xv = 0.f, yv = 0.f;
        if (ceok && ie < ROWS && gre >= 0 && gre < IMG) {
            const int off = base + gre * IMG + gce;
            xv = x[off];
            yv = y[off];
        }
        pfe = make_float2(xv, yv);
    };

    // Commit also derives squares/cross ONCE per input pixel.
    auto commit = [&]() {
        #pragma unroll
        for (int j = 0; j < CHUNK; ++j) {
            const float2 v = pf[j];
            sxy[j][tid] = v;
            ssq[j][tid] = pk_mul(v, v);
            sxc[j][tid] = v.x * v.y;
        }
        if (eact) {
            sxy[je][ce] = pfe;
            ssq[je][ce] = pk_mul(pfe, pfe);
            sxc[je][ce] = pfe.x * pfe.y;
        }
    };

    prefetch(0);
    commit();
    __syncthreads();

    for (int it = 0; it < NCHUNK; ++it) {
        // Issue next chunk's HBM loads NOW; they land during compute below.
        if (it + 1 < NCHUNK) prefetch(it + 1);

        #pragma unroll
        for (int j = 0; j < CHUNK; ++j) {
            const int i = it * CHUNK + j;          // input-row index (uniform)
            if (i < ROWS) {
                // Horizontal 11-tap: pure MACs (2 pk_fma + 1 fma per tap).
                float2 A = make_float2(0.f, 0.f);   // (ax, ay)
                float2 S = make_float2(0.f, 0.f);   // (axx, ayy)
                float  axy = 0.f;
                #pragma unroll
                for (int k = 0; k < KSZ; ++k) {
                    const float2 g2 = gg[(k <= HALO) ? k : (KSZ - 1 - k)];
                    A   = pk_fma(g2, sxy[j][tid + k], A);
                    S   = pk_fma(g2, ssq[j][tid + k], S);
                    axy = fmaf(g2.x, sxc[j][tid + k], axy);
                }
                ringA[j] = A;
                ringS[j] = S;
                ringC[j] = axy;

                // Vertical 11-tap over the ring: 2 pk + 1 fma per tap.
                if (i >= 2 * HALO) {
                    float2 M = make_float2(0.f, 0.f);   // (mx, my)
                    float2 E = make_float2(0.f, 0.f);   // (exx, eyy)
                    float  exy = 0.f;
                    #pragma unroll
                    for (int k = 0; k < KSZ; ++k) {
                        const int s    = (j + 1 + k) % CHUNK;          // static
                        const float2 g2 = gg[(k <= HALO) ? k : (KSZ - 1 - k)];
                        M = pk_fma(g2, ringA[s], M);
                        E = pk_fma(g2, ringS[s], E);
                        exy = fmaf(g2.x, ringC[s], exy);
                    }
                    const float mx = M.x, my = M.y;
                    const float sxv  = E.x - mx * mx;
                    const float syv  = E.y - my * my;
                    const float sxy_ = exy - mx * my;
                    const float num  = (2.f * mx * my + C1) * (2.f * sxy_ + C2);
                    const float den  = (mx * mx + my * my + C1) * (sxv + syv + C2);
                    const float ssim = __fdividef(num, den + 1e-8f);
                    local += (1.f - ssim) * 0.5f;
                }
            }
        }

        // Reuse the single buffer: fence reads, write next chunk, fence writes.
        if (it + 1 < NCHUNK) {
            __syncthreads();   // all reads of this chunk done (WAR)
            commit();
            __syncthreads();   // writes visible before next compute (RAW)
        }
    }

    // ---- block reduction, one atomic per block ----
    #pragma unroll
    for (int o = 32; o > 0; o >>= 1) local += __shfl_down(local, o, 64);
    __shared__ float wsum[4];
    if ((tid & 63) == 0) wsum[tid >> 6] = local;
    __syncthreads();
    if (tid == 0) {
        const float s = wsum[0] + wsum[1] + wsum[2] + wsum[3];
        atomicAdd(out, s * (1.f / 25165824.f));   // / (32*3*512*512)
    }
}

extern "C" void kernel_launch(void* const* d_in, const int* in_sizes, int n_in,
                              void* d_out, int out_size, void* d_ws, size_t ws_size,
                              hipStream_t stream)
{
    const float* x    = (const float*)d_in[0];
    const float* y    = (const float*)d_in[1];
    const float* kern = (const float*)d_in[2];
    float* out = (float*)d_out;

    hipMemsetAsync(out, 0, sizeof(float), stream);

    dim3 grid(IMG / BW, IMG / BH, 32 * 3);   // 2 x 8 x 96 = 1536 blocks
    dssim_strip_kernel<<<grid, BW, 0, stream>>>(x, y, kern, out);
}

// Round 11
// 111.283 us; speedup vs baseline: 1.4082x; 1.4082x over previous
//
#include <hip/hip_runtime.h>

#define IMG    512
#define KSZ    11
#define HALO   5
#define BW     256                  // strip width = blockDim.x
#define BH     64                   // output rows per block
#define INW    (BW + 2*HALO)        // 266 staged columns
#define ROWS   (BH + 2*HALO)        // 74 input rows walked
#define CHUNK  11                   // rows staged per buffer == ring depth
#define NCHUNK ((ROWS + CHUNK - 1) / CHUNK)   // 7

// Packed fp32. R9 lesson: src0 must be a 64-bit *pair* — a lone scalar VGPR
// doesn't assemble. An SGPR pair IS legal (VOP3P: max 1 SGPR source), and
// keeps the 6 (g,g) tap pairs out of the VGPR budget entirely.
__device__ __forceinline__ float2 pk_fma_sg(float2 gs, float2 b, float2 c) {
    float2 d;
    asm("v_pk_fma_f32 %0, %1, %2, %3" : "=v"(d) : "s"(gs), "v"(b), "v"(c));
    return d;
}
__device__ __forceinline__ float2 pk_fma(float2 a, float2 b, float2 c) {
    float2 d;
    asm("v_pk_fma_f32 %0, %1, %2, %3" : "=v"(d) : "v"(a), "v"(b), "v"(c));
    return d;
}
__device__ __forceinline__ float2 pk_mul(float2 a, float2 b) {
    float2 d;
    asm("v_pk_mul_f32 %0, %1, %2" : "=v"(d) : "v"(a), "v"(b));
    return d;
}
__device__ __forceinline__ float2 pk_add(float2 a, float2 b) {
    float2 d;
    asm("v_pk_add_f32 %0, %1, %2" : "=v"(d) : "v"(a), "v"(b));
    return d;
}

__device__ __forceinline__ float rfl(float v) {
    return __uint_as_float(__builtin_amdgcn_readfirstlane(__float_as_uint(v)));
}

// (256,8): pin VGPR<=64 (8 waves/SIMD). Demand after SGPR-ifying the taps is
// ~56-60 (R8 measured 68 with taps in VGPRs) — unlike R3's 112-vs-64 gap.
// Tripwire: WRITE_SIZE must stay bytes, not MB.
__global__ __launch_bounds__(256, 8)
void dssim_strip_kernel(const float* __restrict__ x,
                        const float* __restrict__ y,
                        const float* __restrict__ kern,
                        float* __restrict__ out)
{
    __shared__ float  sg[KSZ];
    // Single staging buffer (23.5 KB) — R10 showed growing LDS kills
    // occupancy and loses more than the staged ALU saves.
    __shared__ float2 sxy[CHUNK][INW + 1];

    const int tid = threadIdx.x;

    // Recover separable 1D gaussian: row sums of the 2D kernel
    // (k2d[i][j] = g[i]*g[j], sum_j = g[i] since sum(g)==1).
    if (tid < KSZ) {
        float s = 0.f;
        #pragma unroll
        for (int j = 0; j < KSZ; ++j) s += kern[tid * KSZ + j];
        sg[tid] = s;
    }
    __syncthreads();

    // Taps are wave-uniform -> hold in SGPRs (readfirstlane), both as
    // scalars (for fmaf) and as (g,g) pairs (for pk ops via "s" operand).
    float  gs[HALO + 1];
    float2 gp[HALO + 1];
    #pragma unroll
    for (int k = 0; k <= HALO; ++k) {
        gs[k] = rfl(sg[k]);
        gp[k] = make_float2(gs[k], gs[k]);
    }

    const int plane = blockIdx.z;                   // n*C + c
    const int base  = plane * IMG * IMG;            // < 25.2M: fits int32
    const int col0  = blockIdx.x * BW;
    const int row0  = blockIdx.y * BH;

    // This thread's staged column (computed once).
    const int  gc  = col0 - HALO + tid;
    const bool cok = (gc >= 0) && (gc < IMG);
    // Remainder columns (INW-BW=10 per row) flattened over threads 0..109:
    const bool eact = (tid < (INW - BW) * CHUNK);
    const int  je   = tid / (INW - BW);             // chunk-local row 0..10
    const int  ce   = BW + tid % (INW - BW);        // LDS col 256..265
    const int  gce  = col0 - HALO + ce;
    const bool ceok = eact && (gce >= 0) && (gce < IMG);

    // Register ring: 11 rows of {(ax,ay),(axx,ayy),axy} — static indexing.
    float2 ringA[CHUNK];
    float2 ringS[CHUNK];
    float  ringC[CHUNK];
    // Prefetch registers for the next chunk (issue-early / write-late).
    float2 pf[CHUNK];
    float2 pfe;

    const float C1 = 1e-4f;    // 0.01^2
    const float C2 = 9e-4f;    // 0.03^2
    float local = 0.f;

    auto prefetch = [&](int cc) {
        #pragma unroll
        for (int j = 0; j < CHUNK; ++j) {
            const int i  = cc * CHUNK + j;
            const int gr = row0 - HALO + i;
            float xv = 0.f, yv = 0.f;
            if (i < ROWS && gr >= 0 && gr < IMG && cok) {
                const int off = base + gr * IMG + gc;
                xv = x[off];
                yv = y[off];
            }
            pf[j] = make_float2(xv, yv);
        }
        const int ie  = cc * CHUNK + je;
        const int gre = row0 - HALO + ie;
        float xv = 0.f, yv = 0.f;
        if (ceok && ie < ROWS && gre >= 0 && gre < IMG) {
            const int off = base + gre * IMG + gce;
            xv = x[off];
            yv = y[off];
        }
        pfe = make_float2(xv, yv);
    };

    auto commit = [&]() {
        #pragma unroll
        for (int j = 0; j < CHUNK; ++j) sxy[j][tid] = pf[j];
        if (eact) sxy[je][ce] = pfe;
    };

    prefetch(0);
    commit();
    __syncthreads();

    for (int it = 0; it < NCHUNK; ++it) {
        // Issue next chunk's HBM loads NOW; they land during compute below.
        if (it + 1 < NCHUNK) prefetch(it + 1);

        #pragma unroll
        for (int j = 0; j < CHUNK; ++j) {
            const int i = it * CHUNK + j;          // input-row index (uniform)
            if (i < ROWS) {
                // Horizontal 11-tap, symmetric pairs (g[k]==g[10-k]):
                // 8 slots/pair + 5 center vs 10/pair unpaired.
                float2 A = make_float2(0.f, 0.f);   // (ax, ay)
                float2 S = make_float2(0.f, 0.f);   // (axx, ayy)
                float  axy = 0.f;
                #pragma unroll
                for (int k = 0; k < HALO; ++k) {
                    const float2 v1 = sxy[j][tid + k];
                    const float2 v2 = sxy[j][tid + (KSZ - 1 - k)];
                    const float2 t  = pk_add(v1, v2);
                    A = pk_fma_sg(gp[k], t, A);
                    const float2 sq = pk_fma(v2, v2, pk_mul(v1, v1));
                    S = pk_fma_sg(gp[k], sq, S);
                    const float c = fmaf(v2.x, v2.y, v1.x * v1.y);
                    axy = fmaf(gs[k], c, axy);
                }
                {   // center tap k=5
                    const float2 v = sxy[j][tid + HALO];
                    A = pk_fma_sg(gp[HALO], v, A);
                    S = pk_fma_sg(gp[HALO], pk_mul(v, v), S);
                    axy = fmaf(gs[HALO], v.x * v.y, axy);
                }
                ringA[j] = A;
                ringS[j] = S;
                ringC[j] = axy;

                // Vertical 11-tap over the ring: 2 pk + 1 fma per tap.
                if (i >= 2 * HALO) {
                    float2 M = make_float2(0.f, 0.f);   // (mx, my)
                    float2 E = make_float2(0.f, 0.f);   // (exx, eyy)
                    float  exy = 0.f;
                    #pragma unroll
                    for (int k = 0; k < KSZ; ++k) {
                        const int s = (j + 1 + k) % CHUNK;             // static
                        const int q = (k <= HALO) ? k : (KSZ - 1 - k);
                        M = pk_fma_sg(gp[q], ringA[s], M);
                        E = pk_fma_sg(gp[q], ringS[s], E);
                        exy = fmaf(gs[q], ringC[s], exy);
                    }
                    const float mx = M.x, my = M.y;
                    const float sxv  = E.x - mx * mx;
                    const float syv  = E.y - my * my;
                    const float sxy_ = exy - mx * my;
                    const float num  = (2.f * mx * my + C1) * (2.f * sxy_ + C2);
                    const float den  = (mx * mx + my * my + C1) * (sxv + syv + C2);
                    const float ssim = __fdividef(num, den + 1e-8f);
                    local += (1.f - ssim) * 0.5f;
                }
            }
        }

        // Reuse the single buffer: fence reads, write next chunk, fence writes.
        if (it + 1 < NCHUNK) {
            __syncthreads();   // all reads of this chunk done (WAR)
            commit();
            __syncthreads();   // writes visible before next compute (RAW)
        }
    }

    // ---- block reduction, one atomic per block ----
    #pragma unroll
    for (int o = 32; o > 0; o >>= 1) local += __shfl_down(local, o, 64);
    __shared__ float wsum[4];
    if ((tid & 63) == 0) wsum[tid >> 6] = local;
    __syncthreads();
    if (tid == 0) {
        const float s = wsum[0] + wsum[1] + wsum[2] + wsum[3];
        atomicAdd(out, s * (1.f / 25165824.f));   // / (32*3*512*512)
    }
}

extern "C" void kernel_launch(void* const* d_in, const int* in_sizes, int n_in,
                              void* d_out, int out_size, void* d_ws, size_t ws_size,
                              hipStream_t stream)
{
    const float* x    = (const float*)d_in[0];
    const float* y    = (const float*)d_in[1];
    const float* kern = (const float*)d_in[2];
    float* out = (float*)d_out;

    hipMemsetAsync(out, 0, sizeof(float), stream);

    dim3 grid(IMG / BW, IMG / BH, 32 * 3);   // 2 x 8 x 96 = 1536 blocks
    dssim_strip_kernel<<<grid, BW, 0, stream>>>(x, y, kern, out);
}

// Round 12
// 92.423 us; speedup vs baseline: 1.6956x; 1.2041x over previous
//
#include <hip/hip_runtime.h>
#include <hip/hip_bf16.h>

#define IMG    512
#define KSZ    11
#define HALO   5
#define STRIP  64          // cols per block
#define PANEL  16          // rows per H panel / V step
#define NSTEP  (IMG/PANEL) // 32 V steps
#define RRING  48          // H ring rows (3 panels live)
#define RPAIR  24          // ring row-pairs
#define FCOLS  74          // staged input cols = STRIP + 2*HALO
#define FSTR   88          // F buffer col stride (bank-spread padding: 176B=44 banks)

typedef short bf16x8 __attribute__((ext_vector_type(8)));
typedef float f32x4  __attribute__((ext_vector_type(4)));

union S8 { bf16x8 v; ushort u16[8]; uint u32[4]; };

__device__ __forceinline__ ushort f2bf(float f) {
    union { __hip_bfloat16 h; ushort u; } c;
    c.h = __float2bfloat16(f);
    return c.u;
}

// MFMA fragment layout assumptions (16x16x32 bf16):
//   A (M=16,K=32): row = lane&15, k = 8*(lane>>4)+i
//   B (K=32,N=16): col = lane&15, k = 8*(lane>>4)+i
//   D (verified, learn_hip m89): col = lane&15, row = 4*(lane>>4)+reg
// Note A and B use the SAME (lane&15, k) mapping -> one Toeplitz fragment
// tg serves as B in the H-pass and as A in the V-pass.
// IF OUTPUT IS GARBAGE: first suspect is the A/B mapping (flip k-major).

__global__ __launch_bounds__(256)
void dssim_mfma_kernel(const float* __restrict__ x,
                       const float* __restrict__ y,
                       const float* __restrict__ kern,
                       float* __restrict__ out)
{
    __shared__ float  sgf[16];
    __shared__ ushort gext[64];
    __shared__ ushort Fbuf[5][PANEL][FSTR];   // bf16 fields {x,y,xx,yy,xy}, 14080 B
    __shared__ ushort Ring[RPAIR][5][68][2];  // bf16 H ring, pair-interleaved, 32640 B
    __shared__ float  wsum[4];

    const int tid = threadIdx.x;
    const int l   = tid & 63;
    const int wv  = tid >> 6;       // wave id 0..3 -> 16-col tile
    const int q   = l >> 4;         // k-group 0..3
    const int cj  = l & 15;         // frag row/col within tile
    const int wcb = wv * 16 + cj;   // strip-local column of my D/B column

    // ---- prologue 1: gaussian row sums; zero LDS that junk-lanes may read ----
    if (tid < KSZ) {
        float s = 0.f;
        #pragma unroll
        for (int j = 0; j < KSZ; ++j) s += kern[tid * KSZ + j];
        sgf[tid] = s;   // k2d rows sum to g (sum(g)==1)
    }
    for (int i = tid; i < 5 * PANEL * FSTR / 2; i += 256) ((uint*)Fbuf)[i] = 0u;
    // ring rows 0..5 = abs rows -5..0 (zero padding above the image)
    for (int i = tid; i < 3 * 5 * 68; i += 256) ((uint*)Ring)[i] = 0u;
    __syncthreads();

    // ---- prologue 2: bf16 tap table gext[16+d] = g[d], else 0 ----
    if (tid < 64) {
        const int d = tid - 16;
        gext[tid] = (d >= 0 && d < KSZ) ? f2bf(sgf[d]) : (ushort)0;
    }
    __syncthreads();

    // ---- Toeplitz fragment: G[k, col] = g[k - col] ----
    S8 tg;
    #pragma unroll
    for (int ii = 0; ii < 8; ++ii)
        tg.u16[ii] = gext[16 + q * 8 + ii - cj];

    const int plane  = blockIdx.z;
    const int cstrip = blockIdx.x * STRIP;
    const int base   = plane * (IMG * IMG);

    // ---- staging map: thread -> (row tid>>4, cols (tid&15)+16m) ----
    const int srow = tid >> 4;
    const int scol = tid & 15;
    int  gcols[5]; bool coks[5];
    #pragma unroll
    for (int m = 0; m < 5; ++m) {
        const int cl = scol + 16 * m;
        gcols[m] = cstrip - HALO + cl;
        coks[m]  = (cl < FCOLS) && (gcols[m] >= 0) && (gcols[m] < IMG);
    }
    float2 pf[5];

    const ushort* aptr = &Fbuf[0][cj][wv * 16 + q * 8];   // A-frag: 8 contiguous bf16

    const float C1 = 1e-4f, C2 = 9e-4f;
    const f32x4 z = {0.f, 0.f, 0.f, 0.f};
    float local = 0.f;

    // prologue: stage panel 0
    {
        const int r  = srow;
        const int rb = base + r * IMG;
        #pragma unroll
        for (int m = 0; m < 5; ++m) {
            float xv = 0.f, yv = 0.f;
            if (coks[m]) { xv = x[rb + gcols[m]]; yv = y[rb + gcols[m]]; }
            pf[m] = make_float2(xv, yv);
        }
        #pragma unroll
        for (int m = 0; m < 5; ++m) {
            const int cl = scol + 16 * m;
            if (cl < FCOLS) {
                const float fx = pf[m].x, fy = pf[m].y;
                Fbuf[0][srow][cl] = f2bf(fx);
                Fbuf[1][srow][cl] = f2bf(fy);
                Fbuf[2][srow][cl] = f2bf(fx * fx);
                Fbuf[3][srow][cl] = f2bf(fy * fy);
                Fbuf[4][srow][cl] = f2bf(fx * fy);
            }
        }
    }
    __syncthreads();

    for (int t = 0; t <= NSTEP; ++t) {
        // ---- H(t): blur panel t horizontally, write bf16 into ring ----
        {
            const int pb = 16 * (t % 3) + HALO;    // ring row base (uniform)
            #pragma unroll
            for (int f = 0; f < 5; ++f) {
                S8 a;
                a.v = *(const bf16x8*)(aptr + f * (PANEL * FSTR));
                f32x4 d = __builtin_amdgcn_mfma_f32_16x16x32_bf16(a.v, tg.v, z, 0, 0, 0);
                #pragma unroll
                for (int r = 0; r < 4; ++r) {
                    int rr = pb + q * 4 + r;       // ring row = (16t + 4q + r + 5) mod 48
                    if (rr >= RRING) rr -= RRING;
                    Ring[rr >> 1][f][wcb][rr & 1] = f2bf(d[r]);
                }
            }
        }

        // ---- prefetch panel t+1 inputs (lands under V below) ----
        if (t < NSTEP) {
            const int r   = (t + 1) * PANEL + srow;
            const bool rok = (r < IMG);
            const int rb  = base + r * IMG;
            #pragma unroll
            for (int m = 0; m < 5; ++m) {
                float xv = 0.f, yv = 0.f;
                if (rok && coks[m]) { xv = x[rb + gcols[m]]; yv = y[rb + gcols[m]]; }
                pf[m] = make_float2(xv, yv);
            }
        }

        __syncthreads();   // ring(t) visible; Fbuf(t) reads done

        // ---- V(t-1): vertical blur from ring + SSIM ----
        if (t >= 1) {
            const int s   = t - 1;
            const int pbs = (8 * s) % RPAIR;
            int pr[4];
            #pragma unroll
            for (int ii = 0; ii < 4; ++ii) {
                int v = pbs + q * 4 + ii;          // pair of ring rows 16s+8q+2ii
                if (v >= RPAIR) v -= RPAIR;
                pr[ii] = v;
            }
            f32x4 vf[5];
            #pragma unroll
            for (int f = 0; f < 5; ++f) {
                S8 b;
                #pragma unroll
                for (int ii = 0; ii < 4; ++ii)
                    b.u32[ii] = *(const uint*)&Ring[pr[ii]][f][wcb][0];
                vf[f] = __builtin_amdgcn_mfma_f32_16x16x32_bf16(tg.v, b.v, z, 0, 0, 0);
            }
            #pragma unroll
            for (int r = 0; r < 4; ++r) {
                const float mx  = vf[0][r], my  = vf[1][r];
                const float exx = vf[2][r], eyy = vf[3][r], exy = vf[4][r];
                const float sxv = fmaf(-mx, mx, exx);
                const float syv = fmaf(-my, my, eyy);
                const float sxy = fmaf(-mx, my, exy);
                const float num = fmaf(2.f, mx * my, C1) * fmaf(2.f, sxy, C2);
                const float den = fmaf(mx, mx, fmaf(my, my, C1)) * (sxv + syv + C2);
                const float ssim = __fdividef(num, den + 1e-8f);
                local += (1.f - ssim) * 0.5f;
            }
        }

        // ---- commit panel t+1 into Fbuf (reads of panel t fenced above) ----
        if (t < NSTEP) {
            #pragma unroll
            for (int m = 0; m < 5; ++m) {
                const int cl = scol + 16 * m;
                if (cl < FCOLS) {
                    const float fx = pf[m].x, fy = pf[m].y;
                    Fbuf[0][srow][cl] = f2bf(fx);
                    Fbuf[1][srow][cl] = f2bf(fy);
                    Fbuf[2][srow][cl] = f2bf(fx * fx);
                    Fbuf[3][srow][cl] = f2bf(fy * fy);
                    Fbuf[4][srow][cl] = f2bf(fx * fy);
                }
            }
        }
        __syncthreads();   // Fbuf(t+1) visible for H(t+1)
    }

    // ---- block reduction, one atomic per block ----
    #pragma unroll
    for (int o = 32; o > 0; o >>= 1) local += __shfl_down(local, o, 64);
    if (l == 0) wsum[wv] = local;
    __syncthreads();
    if (tid == 0) {
        const float s = wsum[0] + wsum[1] + wsum[2] + wsum[3];
        atomicAdd(out, s * (1.f / 25165824.f));   // / (32*3*512*512)
    }
}

extern "C" void kernel_launch(void* const* d_in, const int* in_sizes, int n_in,
                              void* d_out, int out_size, void* d_ws, size_t ws_size,
                              hipStream_t stream)
{
    const float* x    = (const float*)d_in[0];
    const float* y    = (const float*)d_in[1];
    const float* kern = (const float*)d_in[2];
    float* out = (float*)d_out;

    hipMemsetAsync(out, 0, sizeof(float), stream);

    dim3 grid(IMG / STRIP, 1, 32 * 3);   // 8 strips x 96 planes = 768 = 3/CU
    dssim_mfma_kernel<<<grid, 256, 0, stream>>>(x, y, kern, out);
}

// Round 13
// 81.538 us; speedup vs baseline: 1.9219x; 1.1335x over previous
//
#include <hip/hip_runtime.h>
#include <hip/hip_bf16.h>

#define IMG    512
#define KSZ    11
#define HALO   5
#define STRIP  64          // cols per block
#define PANEL  16          // rows per H panel / V step
#define NSTEP  32          // IMG/PANEL
#define PAIRS  37          // ceil((STRIP+2*HALO)/2) staged col-pairs
#define FSTR32 44          // Fbuf row stride in u32 (37 pairs + 7 pad)
#define FROW   704         // PANEL*FSTR32 (u32 per field)
#define RSTR32 340         // Ring pair-row stride in u32 (5 fields * 68 cols)

typedef short bf16x8 __attribute__((ext_vector_type(8)));
typedef float f32x4  __attribute__((ext_vector_type(4)));
union S8 { bf16x8 v; ushort u16[8]; uint u32[4]; };

__device__ __forceinline__ uint cvtpk(float lo, float hi) {
    uint r;
    asm("v_cvt_pk_bf16_f32 %0, %1, %2" : "=v"(r) : "v"(lo), "v"(hi));
    return r;
}
__device__ __forceinline__ float2 pk_mul(float2 a, float2 b) {
    float2 d;
    asm("v_pk_mul_f32 %0, %1, %2" : "=v"(d) : "v"(a), "v"(b));
    return d;
}
__device__ __forceinline__ ushort f2bf(float f) {   // prologue-only scalar cvt
    union { __hip_bfloat16 h; ushort u; } c;
    c.h = __float2bfloat16(f);
    return c.u;
}

// MFMA 16x16x32 bf16 fragment layouts (validated end-to-end by R12 passing):
//   A: row = lane&15, k = 8*(lane>>4)+i    B: col = lane&15, k = 8*(lane>>4)+i
//   D: col = lane&15, row = 4*(lane>>4)+reg  (learn_hip m89)
// Ring row = abs_row + 6 (mod 48). H writes rows 16t+4q+{0..3}+6 -> EVEN base
// -> two pair-aligned u32 writes (cvt_pk d0d1 / d2d3).
// V(s): D[j] = sum_K g[K-j-1] * ring[16s+K], K=0..31 (shifted Toeplitz tgv);
// out-of-band K multiply finite data by g=0.

__global__ __launch_bounds__(256)
void dssim_mfma_kernel(const float* __restrict__ x,
                       const float* __restrict__ y,
                       const float* __restrict__ kern,
                       float* __restrict__ out)
{
    __shared__ float  sgf[16];
    __shared__ ushort gext[64];
    __shared__ uint   Fbuf32[5 * FROW];     // 3520 u32 = 14080 B, bf16 col-pairs
    __shared__ uint   Ring32[24 * RSTR32];  // 8160 u32 = 32640 B, row-pair packed
    __shared__ float  wsum[4];

    const int tid = threadIdx.x;
    const int l   = tid & 63;
    const int wv  = tid >> 6;       // wave -> 16-col tile
    const int q   = l >> 4;         // k-group
    const int cj  = l & 15;
    const int wcb = wv * 16 + cj;   // strip-local column

    // ---- prologue: taps; zero Fbuf pad + ring pad rows 0..5 ----
    if (tid < KSZ) {
        float s = 0.f;
        #pragma unroll
        for (int j = 0; j < KSZ; ++j) s += kern[tid * KSZ + j];
        sgf[tid] = s;   // k2d rows sum to g (sum(g)==1)
    }
    for (int i = tid; i < 5 * FROW; i += 256) Fbuf32[i] = 0u;
    for (int i = tid; i < 3 * RSTR32; i += 256) Ring32[i] = 0u;
    __syncthreads();
    if (tid < 64) {
        const int d = tid - 16;
        gext[tid] = (d >= 0 && d < KSZ) ? f2bf(sgf[d]) : (ushort)0;
    }
    __syncthreads();

    // Toeplitz fragments: H B-frag g[k-col]; V A-frag g[K-row-1] (parity shift)
    S8 tgh, tgv;
    #pragma unroll
    for (int ii = 0; ii < 8; ++ii) {
        tgh.u16[ii] = gext[16 + q * 8 + ii - cj];
        tgv.u16[ii] = gext[15 + q * 8 + ii - cj];
    }

    const int plane  = blockIdx.z;
    const int cstrip = blockIdx.x * STRIP;
    const int base   = plane * (IMG * IMG);

    // ---- staging map: thread -> (row tid>>4, col-pairs (tid&15)+16m) ----
    const int srow = tid >> 4;
    const int sp   = tid & 15;
    int gcol0[3], gcol1[3], wo[3];
    bool ok0[3], ok1[3];
    #pragma unroll
    for (int m = 0; m < 3; ++m) {
        const int p  = sp + 16 * m;
        const bool pa = (p < PAIRS);
        const int c0 = cstrip - HALO + 2 * p;
        gcol0[m] = c0;  gcol1[m] = c0 + 1;
        ok0[m] = pa && (c0 >= 0) && (c0 < IMG);
        ok1[m] = pa && (c0 + 1 >= 0) && (c0 + 1 < IMG);
        wo[m]  = srow * FSTR32 + p;
    }
    float2 px[3], py[3];

    auto prefetch = [&](int pn) {
        const int r    = pn * PANEL + srow;
        const bool rok = (r < IMG);
        const int rb   = base + r * IMG;
        #pragma unroll
        for (int m = 0; m < 3; ++m) {
            float a0 = 0.f, a1 = 0.f, b0 = 0.f, b1 = 0.f;
            if (rok && ok0[m]) { a0 = x[rb + gcol0[m]]; b0 = y[rb + gcol0[m]]; }
            if (rok && ok1[m]) { a1 = x[rb + gcol1[m]]; b1 = y[rb + gcol1[m]]; }
            px[m] = make_float2(a0, a1);
            py[m] = make_float2(b0, b1);
        }
    };
    auto commit = [&]() {
        #pragma unroll
        for (int m = 0; m < 3; ++m) {
            if (m < 2 || sp < PAIRS - 32) {        // pairs 32..36 only
                const float2 vx = px[m], vy = py[m];
                const float2 xx = pk_mul(vx, vx);
                const float2 yy = pk_mul(vy, vy);
                const float2 xy = pk_mul(vx, vy);
                Fbuf32[0 * FROW + wo[m]] = cvtpk(vx.x, vx.y);
                Fbuf32[1 * FROW + wo[m]] = cvtpk(vy.x, vy.y);
                Fbuf32[2 * FROW + wo[m]] = cvtpk(xx.x, xx.y);
                Fbuf32[3 * FROW + wo[m]] = cvtpk(yy.x, yy.y);
                Fbuf32[4 * FROW + wo[m]] = cvtpk(xy.x, xy.y);
            }
        }
    };

    prefetch(0);
    commit();
    __syncthreads();

    const f32x4 z0 = {0.f, 0.f, 0.f, 0.f};
    const float C1 = 1e-4f, C2 = 9e-4f;
    const int aoff = cj * FSTR32 + wv * 8 + q * 4;   // A-frag u32 offset
    float local = 0.f;
    int hb = 0, vb = 16;                              // (8t)%24, (8(t-1))%24

    for (int t = 0; t <= NSTEP; ++t) {
        // ---- H(t): panel -> ring, packed pair writes ----
        {
            int p0 = hb + 2 * q + 3;  if (p0 >= 24) p0 -= 24;
            int p1 = p0 + 1;          if (p1 >= 24) p1 -= 24;
            const int rw0 = p0 * RSTR32 + wcb;
            const int rw1 = p1 * RSTR32 + wcb;
            #pragma unroll
            for (int f = 0; f < 5; ++f) {
                S8 a;
                a.v = *(const bf16x8*)&Fbuf32[f * FROW + aoff];
                f32x4 d = __builtin_amdgcn_mfma_f32_16x16x32_bf16(a.v, tgh.v, z0, 0, 0, 0);
                Ring32[rw0 + f * 68] = cvtpk(d[0], d[1]);
                Ring32[rw1 + f * 68] = cvtpk(d[2], d[3]);
            }
        }

        if (t < NSTEP) prefetch(t + 1);   // HBM lands under V below

        __syncthreads();   // ring(t) visible; Fbuf(t) reads done

        // ---- V(t-1) + SSIM ----
        if (t >= 1) {
            int vr[4];
            #pragma unroll
            for (int ii = 0; ii < 4; ++ii) {
                int pp = vb + 4 * q + ii;  if (pp >= 24) pp -= 24;
                vr[ii] = pp * RSTR32 + wcb;
            }
            f32x4 vf[5];
            #pragma unroll
            for (int f = 0; f < 5; ++f) {
                S8 b;
                #pragma unroll
                for (int ii = 0; ii < 4; ++ii) b.u32[ii] = Ring32[vr[ii] + f * 68];
                vf[f] = __builtin_amdgcn_mfma_f32_16x16x32_bf16(tgv.v, b.v, z0, 0, 0, 0);
            }
            #pragma unroll
            for (int r = 0; r < 4; ++r) {
                const float mx  = vf[0][r], my  = vf[1][r];
                const float exx = vf[2][r], eyy = vf[3][r], exy = vf[4][r];
                const float sxv = fmaf(-mx, mx, exx);
                const float syv = fmaf(-my, my, eyy);
                const float sxy = fmaf(-mx, my, exy);
                const float num = fmaf(2.f, mx * my, C1) * fmaf(2.f, sxy, C2);
                const float den = fmaf(mx, mx, fmaf(my, my, C1)) * (sxv + syv + C2);
                const float ssim = __fdividef(num, den + 1e-8f);
                local += (1.f - ssim) * 0.5f;
            }
        }

        if (t < NSTEP) commit();          // panel t+1 (WAR fenced above)
        __syncthreads();                  // Fbuf(t+1) + ring reads done

        vb = hb;
        hb += 8;  if (hb >= 24) hb -= 24;
    }

    // ---- block reduction, one atomic per block ----
    #pragma unroll
    for (int o = 32; o > 0; o >>= 1) local += __shfl_down(local, o, 64);
    if (l == 0) wsum[wv] = local;
    __syncthreads();
    if (tid == 0) {
        const float s = wsum[0] + wsum[1] + wsum[2] + wsum[3];
        atomicAdd(out, s * (1.f / 25165824.f));   // / (32*3*512*512)
    }
}

extern "C" void kernel_launch(void* const* d_in, const int* in_sizes, int n_in,
                              void* d_out, int out_size, void* d_ws, size_t ws_size,
                              hipStream_t stream)
{
    const float* x    = (const float*)d_in[0];
    const float* y    = (const float*)d_in[1];
    const float* kern = (const float*)d_in[2];
    float* out = (float*)d_out;

    hipMemsetAsync(out, 0, sizeof(float), stream);

    dim3 grid(IMG / STRIP, 1, 32 * 3);   // 8 strips x 96 planes = 768 = 3/CU
    dssim_mfma_kernel<<<grid, 256, 0, stream>>>(x, y, kern, out);
}

// Round 14
// 81.375 us; speedup vs baseline: 1.9258x; 1.0020x over previous
//
#include <hip/hip_runtime.h>
#include <hip/hip_bf16.h>

#define IMG    512
#define KSZ    11
#define HALO   5
#define STRIP  64          // cols per block (4 waves x 16)
#define PANEL  16          // rows per H panel / V step
#define RSTR32 330         // ring pair-row stride in u32 (5 fields * 66)
#define FOFF   66          // per-field offset within a ring pair-row (u32)

typedef short bf16x8 __attribute__((ext_vector_type(8)));
typedef float f32x4  __attribute__((ext_vector_type(4)));
union S8 { bf16x8 v; ushort u16[8]; uint u32[4]; };

__device__ __forceinline__ uint cvtpk(float lo, float hi) {
    uint r;
    asm("v_cvt_pk_bf16_f32 %0, %1, %2" : "=v"(r) : "v"(lo), "v"(hi));
    return r;
}
__device__ __forceinline__ float2 pk_mul(float2 a, float2 b) {
    float2 d;
    asm("v_pk_mul_f32 %0, %1, %2" : "=v"(d) : "v"(a), "v"(b));
    return d;
}
__device__ __forceinline__ ushort f2bf(float f) {   // prologue-only
    union { __hip_bfloat16 h; ushort u; } c;
    c.h = __float2bfloat16(f);
    return c.u;
}

// MFMA 16x16x32 bf16 layouts (validated end-to-end R12/R13):
//   A: row=lane&15, k=8*(lane>>4)+i   B: col=lane&15, k=8*(lane>>4)+i
//   D: col=lane&15, row=4*(lane>>4)+reg
// NEW: A-frags sourced DIRECTLY from global (no Fbuf): lane (q,cj) loads
// panel row cj, cols cstrip-8+16wv+8q+{0..7} (8-aligned -> 2x float4,
// spans never straddle the image edge since 512%8==0).
// H Toeplitz: weight g[k-cj-3] (window shift -8); table slot 18+d.
// Ring row = abs+6 mod 48 (pair-packed u32), same as R13.

__global__ __launch_bounds__(256)
void dssim_mfma_kernel(const float* __restrict__ x,
                       const float* __restrict__ y,
                       const float* __restrict__ kern,
                       float* __restrict__ out)
{
    __shared__ float  sgf[16];
    __shared__ ushort gext[64];
    __shared__ uint   Ring32[24 * RSTR32];   // 31680 B — ONLY big LDS left
    __shared__ float  wsum[4];

    const int tid = threadIdx.x;
    const int l   = tid & 63;
    const int wv  = tid >> 6;
    const int q   = l >> 4;
    const int cj  = l & 15;
    const int wcb = wv * 16 + cj;

    if (tid < KSZ) {
        float s = 0.f;
        #pragma unroll
        for (int j = 0; j < KSZ; ++j) s += kern[tid * KSZ + j];
        sgf[tid] = s;   // k2d rows sum to g (sum(g)==1)
    }
    for (int i = tid; i < 3 * RSTR32; i += 256) Ring32[i] = 0u;  // pad rows 0..5
    __syncthreads();
    if (tid < 64) {
        const int d = tid - 18;                    // slot 18+d holds g[d]
        gext[tid] = (d >= 0 && d < KSZ) ? f2bf(sgf[d]) : (ushort)0;
    }
    __syncthreads();

    // Toeplitz frags: H g[k-cj-3] -> slot 15+k-cj (in [0,46]);
    //                 V g[k-cj-1] -> slot 17+k-cj (in [2,48]).
    S8 tgh, tgv;
    #pragma unroll
    for (int ii = 0; ii < 8; ++ii) {
        tgh.u16[ii] = gext[15 + q * 8 + ii - cj];
        tgv.u16[ii] = gext[17 + q * 8 + ii - cj];
    }

    const int plane  = blockIdx.z;
    const int half   = blockIdx.y;
    const int cstrip = blockIdx.x * STRIP;
    const int base   = plane * (IMG * IMG);

    const int  cb    = cstrip - 8 + 16 * wv + 8 * q;   // multiple of 8
    const bool colok = (cb >= 0) && (cb + 8 <= IMG);
    const float* xp  = x + base + cb;
    const float* yp  = y + base + cb;

    // Row-split: h=0 does V(0..15) via t=0..16; h=1 primes t=15,16 then
    // V(16..31) via t=17..32. 2 extra H panels per half.
    const int t0   = half ? 15 : 0;
    const int t1   = half ? 32 : 16;
    const int vmin = half ? 17 : 1;

    f32x4 xa, xb, ya, yb;
    auto load8 = [&](int t) {
        const int r = t * PANEL + cj;
        if (r < IMG && colok) {
            const float* px = xp + r * IMG;
            const float* py = yp + r * IMG;
            xa = *(const f32x4*)px;  xb = *(const f32x4*)(px + 4);
            ya = *(const f32x4*)py;  yb = *(const f32x4*)(py + 4);
        } else {
            const f32x4 zz = {0.f, 0.f, 0.f, 0.f};
            xa = zz; xb = zz; ya = zz; yb = zz;
        }
    };

    load8(t0);

    const f32x4 z0 = {0.f, 0.f, 0.f, 0.f};
    const float C1 = 1e-4f, C2 = 9e-4f;
    float local = 0.f;
    int hb = (8 * t0) % 24;

    for (int t = t0; t <= t1; ++t) {
        // ---- build 5 bf16 A-frags in registers ----
        float2 x01 = {xa[0], xa[1]}, x23 = {xa[2], xa[3]};
        float2 x45 = {xb[0], xb[1]}, x67 = {xb[2], xb[3]};
        float2 y01 = {ya[0], ya[1]}, y23 = {ya[2], ya[3]};
        float2 y45 = {yb[0], yb[1]}, y67 = {yb[2], yb[3]};
        S8 fx, fy, fxx, fyy, fxy;
        #pragma unroll
        for (int w = 0; w < 4; ++w) {
            const float2 xv = (w == 0) ? x01 : (w == 1) ? x23 : (w == 2) ? x45 : x67;
            const float2 yv = (w == 0) ? y01 : (w == 1) ? y23 : (w == 2) ? y45 : y67;
            const float2 xxv = pk_mul(xv, xv);
            const float2 yyv = pk_mul(yv, yv);
            const float2 xyv = pk_mul(xv, yv);
            fx .u32[w] = cvtpk(xv.x,  xv.y);
            fy .u32[w] = cvtpk(yv.x,  yv.y);
            fxx.u32[w] = cvtpk(xxv.x, xxv.y);
            fyy.u32[w] = cvtpk(yyv.x, yyv.y);
            fxy.u32[w] = cvtpk(xyv.x, xyv.y);
        }

        if (t < t1) load8(t + 1);   // HBM latency hides under MFMA + V below

        // ---- H(t): 5 MFMAs -> pair-packed ring writes ----
        {
            int p0 = hb + 2 * q + 3;  if (p0 >= 24) p0 -= 24;
            int p1 = p0 + 1;          if (p1 >= 24) p1 -= 24;
            const int rw0 = p0 * RSTR32 + wcb;
            const int rw1 = p1 * RSTR32 + wcb;
            f32x4 d;
            d = __builtin_amdgcn_mfma_f32_16x16x32_bf16(fx.v,  tgh.v, z0, 0, 0, 0);
            Ring32[rw0 + 0 * FOFF] = cvtpk(d[0], d[1]);
            Ring32[rw1 + 0 * FOFF] = cvtpk(d[2], d[3]);
            d = __builtin_amdgcn_mfma_f32_16x16x32_bf16(fy.v,  tgh.v, z0, 0, 0, 0);
            Ring32[rw0 + 1 * FOFF] = cvtpk(d[0], d[1]);
            Ring32[rw1 + 1 * FOFF] = cvtpk(d[2], d[3]);
            d = __builtin_amdgcn_mfma_f32_16x16x32_bf16(fxx.v, tgh.v, z0, 0, 0, 0);
            Ring32[rw0 + 2 * FOFF] = cvtpk(d[0], d[1]);
            Ring32[rw1 + 2 * FOFF] = cvtpk(d[2], d[3]);
            d = __builtin_amdgcn_mfma_f32_16x16x32_bf16(fyy.v, tgh.v, z0, 0, 0, 0);
            Ring32[rw0 + 3 * FOFF] = cvtpk(d[0], d[1]);
            Ring32[rw1 + 3 * FOFF] = cvtpk(d[2], d[3]);
            d = __builtin_amdgcn_mfma_f32_16x16x32_bf16(fxy.v, tgh.v, z0, 0, 0, 0);
            Ring32[rw0 + 4 * FOFF] = cvtpk(d[0], d[1]);
            Ring32[rw1 + 4 * FOFF] = cvtpk(d[2], d[3]);
        }

        __syncthreads();   // ring(t) visible

        // ---- V(t-1) + SSIM ----
        if (t >= vmin) {
            const int vb = (hb >= 8) ? hb - 8 : hb + 16;   // (8(t-1)) mod 24
            int vr[4];
            #pragma unroll
            for (int ii = 0; ii < 4; ++ii) {
                int pp = vb + 4 * q + ii;  if (pp >= 24) pp -= 24;
                vr[ii] = pp * RSTR32 + wcb;
            }
            f32x4 vf[5];
            #pragma unroll
            for (int f = 0; f < 5; ++f) {
                S8 b;
                #pragma unroll
                for (int ii = 0; ii < 4; ++ii) b.u32[ii] = Ring32[vr[ii] + f * FOFF];
                vf[f] = __builtin_amdgcn_mfma_f32_16x16x32_bf16(tgv.v, b.v, z0, 0, 0, 0);
            }
            #pragma unroll
            for (int r = 0; r < 4; ++r) {
                const float mx  = vf[0][r], my  = vf[1][r];
                const float exx = vf[2][r], eyy = vf[3][r], exy = vf[4][r];
                const float sxv = fmaf(-mx, mx, exx);
                const float syv = fmaf(-my, my, eyy);
                const float sxy = fmaf(-mx, my, exy);
                const float num = fmaf(2.f, mx * my, C1) * fmaf(2.f, sxy, C2);
                const float den = fmaf(mx, mx, fmaf(my, my, C1)) * (sxv + syv + C2);
                const float ssim = __fdividef(num, den + 1e-8f);
                local += (1.f - ssim) * 0.5f;
            }
        }

        __syncthreads();   // WAR: V reads done before H(t+1) overwrites

        hb += 8;  if (hb >= 24) hb -= 24;
    }

    // ---- block reduction, one atomic per block ----
    #pragma unroll
    for (int o = 32; o > 0; o >>= 1) local += __shfl_down(local, o, 64);
    if (l == 0) wsum[wv] = local;
    __syncthreads();
    if (tid == 0) {
        const float s = wsum[0] + wsum[1] + wsum[2] + wsum[3];
        atomicAdd(out, s * (1.f / 25165824.f));   // / (32*3*512*512)
    }
}

extern "C" void kernel_launch(void* const* d_in, const int* in_sizes, int n_in,
                              void* d_out, int out_size, void* d_ws, size_t ws_size,
                              hipStream_t stream)
{
    const float* x    = (const float*)d_in[0];
    const float* y    = (const float*)d_in[1];
    const float* kern = (const float*)d_in[2];
    float* out = (float*)d_out;

    hipMemsetAsync(out, 0, sizeof(float), stream);

    dim3 grid(IMG / STRIP, 2, 32 * 3);   // 8 strips x 2 halves x 96 planes
    dssim_mfma_kernel<<<grid, 256, 0, stream>>>(x, y, kern, out);
}